// Round 4
// baseline (481.228 us; speedup 1.0000x reference)
//
#include <hip/hip_runtime.h>
#include <hip/hip_bf16.h>

#define B_    32
#define C_    512
#define S_    1024
#define G_    32
#define CPG_  16
#define C3_   1536
#define EPS_  1e-5f
#define SCALE_ 0.044194173824159216f   // 1/sqrt(512)
#define PSCL_  256.0f                  // P pre-scale before fp8 (keeps P in e4m3 normal range)
#define IPSCL_ 0.00390625f             // 1/256, folded into PV epilogue

typedef __attribute__((ext_vector_type(4))) float floatx4;

// pack 4 floats -> 4 fp8 e4m3 bytes (a=byte0 .. d=byte3)
__device__ __forceinline__ unsigned int f2fp8x4(float a, float b, float c, float d) {
    int v = __builtin_amdgcn_cvt_pk_fp8_f32(a, b, 0, false);
    v = __builtin_amdgcn_cvt_pk_fp8_f32(c, d, v, true);
    return (unsigned int)v;
}

// direct global->LDS DMA, 16 bytes per lane. LDS dest = wave-uniform base + lane*16.
__device__ __forceinline__ void gl16(const unsigned char* g, unsigned char* l) {
    __builtin_amdgcn_global_load_lds(
        (const __attribute__((address_space(1))) unsigned int*)g,
        (__attribute__((address_space(3))) unsigned int*)l, 16, 0, 0);
}

// ---------------- group-norm stats ----------------
__global__ __launch_bounds__(256) void gn_stats(const float* __restrict__ x,
                                                float2* __restrict__ stats) {
    const size_t base = (size_t)blockIdx.x * (CPG_ * S_);
    const float4* xp = (const float4*)(x + base);
    float s = 0.f, ss = 0.f;
    for (int i = threadIdx.x; i < (CPG_ * S_) / 4; i += 256) {
        float4 v = xp[i];
        s  += v.x + v.y + v.z + v.w;
        ss += v.x * v.x + v.y * v.y + v.z * v.z + v.w * v.w;
    }
    #pragma unroll
    for (int o = 32; o; o >>= 1) { s += __shfl_down(s, o); ss += __shfl_down(ss, o); }
    __shared__ float a1[4], a2[4];
    const int wid = threadIdx.x >> 6, lane = threadIdx.x & 63;
    if (lane == 0) { a1[wid] = s; a2[wid] = ss; }
    __syncthreads();
    if (threadIdx.x == 0) {
        float S  = a1[0] + a1[1] + a1[2] + a1[3];
        float SS = a2[0] + a2[1] + a2[2] + a2[3];
        float mean = S * (1.f / 16384.f);
        float var  = SS * (1.f / 16384.f) - mean * mean;
        stats[blockIdx.x] = make_float2(mean, rsqrtf(var + EPS_));
    }
}

// ---------------- fp32 -> fp8 convert (weights) ----------------
__global__ __launch_bounds__(256) void cast_fp8(const float* __restrict__ src,
                                                unsigned char* __restrict__ dst) {
    int i = (blockIdx.x * 256 + threadIdx.x) * 4;
    float4 v = *(const float4*)(src + i);
    *(unsigned int*)(dst + i) = f2fp8x4(v.x, v.y, v.z, v.w);
}

// ---------------- normalized x, transposed to [b][s][c], fp8 ----------------
__global__ __launch_bounds__(256) void xnt_kernel(const float* __restrict__ x,
                                                  const float* __restrict__ gamma,
                                                  const float* __restrict__ beta,
                                                  const float2* __restrict__ stats,
                                                  unsigned char* __restrict__ xnt) {
    const int b = blockIdx.z, c0 = blockIdx.y * 64, s0 = blockIdx.x * 64;
    __shared__ float tile[64][65];
    const float* xb = x + (size_t)b * (C_ * S_);
    const int t = threadIdx.x, tr = t >> 4, tc4 = (t & 15) * 4;
    #pragma unroll
    for (int i = 0; i < 4; i++) {
        int r = tr + i * 16;
        int c = c0 + r;
        float2 mv = stats[b * G_ + (c >> 4)];
        float a  = mv.y * gamma[c];
        float bb = beta[c] - mv.x * a;
        float4 v = *(const float4*)(xb + (size_t)c * S_ + s0 + tc4);
        tile[r][tc4 + 0] = a * v.x + bb;
        tile[r][tc4 + 1] = a * v.y + bb;
        tile[r][tc4 + 2] = a * v.z + bb;
        tile[r][tc4 + 3] = a * v.w + bb;
    }
    __syncthreads();
    unsigned char* xo = xnt + (size_t)b * (S_ * C_);
    #pragma unroll
    for (int i = 0; i < 4; i++) {
        int sr = tr + i * 16;
        *(unsigned int*)(xo + (size_t)(s0 + sr) * C_ + c0 + tc4) =
            f2fp8x4(tile[tc4 + 0][sr], tile[tc4 + 1][sr],
                    tile[tc4 + 2][sr], tile[tc4 + 3][sr]);
    }
}

// ---------------- fp8 MFMA 128x128 mainloop, BK=64, global_load_lds ----------------
// C[m][n] = sum_k A[m][k]*B[n][k]; A,B fp8 K-contiguous, unpadded LDS [128][64] bytes.
// mfma(X,Y): D col(lane&15) <-> Y's rows, D row(quad) <-> X's rows (verified R2).
template<bool SWAP>
__device__ __forceinline__ void mfma_loop(const unsigned char* __restrict__ Ag, int lda,
                                          const unsigned char* __restrict__ Bg, int ldb,
                                          int K, int m0, int n0,
                                          unsigned char* ldsA, unsigned char* ldsB,
                                          floatx4 (&acc)[4][4]) {
    const int t = threadIdx.x, lane = t & 63, wave = t >> 6;
    const int wr = (wave >> 1) * 64, wc = (wave & 1) * 64;
    const int lrow = lane & 15, lq = lane >> 4;
    // staging: per issue a wave covers 1024 B = 16 rows x 64 B.
    const int srow = wave * 16 + (lane >> 2);
    const int scol = (lane & 3) * 16;
    unsigned char* lA0 = ldsA + wave * 1024;
    unsigned char* lA1 = ldsA + 4096 + wave * 1024;
    unsigned char* lB0 = ldsB + wave * 1024;
    unsigned char* lB1 = ldsB + 4096 + wave * 1024;
    const unsigned char* gA0 = Ag + (size_t)(m0 + srow) * lda + scol;
    const unsigned char* gA1 = gA0 + (size_t)64 * lda;
    const unsigned char* gB0 = Bg + (size_t)(n0 + srow) * ldb + scol;
    const unsigned char* gB1 = gB0 + (size_t)64 * ldb;
    for (int k0 = 0; k0 < K; k0 += 64) {
        gl16(gA0 + k0, lA0);
        gl16(gA1 + k0, lA1);
        gl16(gB0 + k0, lB0);
        gl16(gB1 + k0, lB1);
        __syncthreads();
        #pragma unroll
        for (int kc = 0; kc < 2; kc++) {
            long af[4], bfr[4];
            #pragma unroll
            for (int i = 0; i < 4; i++) {
                af[i]  = *(const long*)(ldsA + (wr + i * 16 + lrow) * 64 + kc * 32 + lq * 8);
                bfr[i] = *(const long*)(ldsB + (wc + i * 16 + lrow) * 64 + kc * 32 + lq * 8);
            }
            #pragma unroll
            for (int i = 0; i < 4; i++)
                #pragma unroll
                for (int j = 0; j < 4; j++) {
                    if (SWAP)
                        acc[i][j] = __builtin_amdgcn_mfma_f32_16x16x32_fp8_fp8(bfr[j], af[i], acc[i][j], 0, 0, 0);
                    else
                        acc[i][j] = __builtin_amdgcn_mfma_f32_16x16x32_fp8_fp8(af[i], bfr[j], acc[i][j], 0, 0, 0);
                }
        }
        __syncthreads();
    }
}

#define GEMM_PROLOGUE                                                   \
    __shared__ __align__(16) unsigned char ldsA[128 * 64];              \
    __shared__ __align__(16) unsigned char ldsB[128 * 64];              \
    const int b = blockIdx.z;                                           \
    const int m0 = blockIdx.y * 128, n0 = blockIdx.x * 128;             \
    const int t = threadIdx.x, lane = t & 63, wave = t >> 6;            \
    const int wr = (wave >> 1) * 64, wc = (wave & 1) * 64;              \
    const int lrow = lane & 15, lq = lane >> 4;                         \
    floatx4 acc[4][4];                                                  \
    _Pragma("unroll") for (int i = 0; i < 4; i++)                       \
        _Pragma("unroll") for (int j = 0; j < 4; j++)                   \
            acc[i][j] = (floatx4){0.f, 0.f, 0.f, 0.f};

// ---------------- QKV projection ----------------
// A = wqkv_fp8 [1536][512], B = xnt[b] [1024][512].
// m-tiles 0-7 -> Q,K stored [s][c] fp8, 8-11 -> V[c][s] fp8 (SWAP).
__global__ __launch_bounds__(256) void qkv_mfma(const unsigned char* __restrict__ wq,
                                                const unsigned char* __restrict__ xnt,
                                                const float* __restrict__ bias,
                                                unsigned char* __restrict__ Qb,
                                                unsigned char* __restrict__ Kb,
                                                unsigned char* __restrict__ Vb) {
    GEMM_PROLOGUE
    const unsigned char* Bg = xnt + (size_t)b * (S_ * C_);
    if (m0 < 1024) {
        mfma_loop<false>(wq, C_, Bg, C_, C_, m0, n0, ldsA, ldsB, acc);
        unsigned char* dst = (m0 < 512 ? Qb : Kb) + (size_t)b * (S_ * C_);
        const int osec = (m0 < 512) ? 0 : 512;
        #pragma unroll
        for (int i = 0; i < 4; i++)
            #pragma unroll
            for (int j = 0; j < 4; j++) {
                int oabs = m0 + wr + i * 16 + lq * 4;   // 4 contiguous o (quad rows)
                int s    = n0 + wc + j * 16 + lrow;     // col
                float4 bi = *(const float4*)(bias + oabs);
                floatx4 v = acc[i][j];
                *(unsigned int*)(dst + (size_t)s * C_ + (oabs - osec)) =
                    f2fp8x4(v[0] + bi.x, v[1] + bi.y, v[2] + bi.z, v[3] + bi.w);
            }
    } else {
        mfma_loop<true>(wq, C_, Bg, C_, C_, m0, n0, ldsA, ldsB, acc);
        unsigned char* dst = Vb + (size_t)b * (C_ * S_);
        #pragma unroll
        for (int i = 0; i < 4; i++)
            #pragma unroll
            for (int j = 0; j < 4; j++) {
                int c  = m0 - 1024 + wr + i * 16 + lrow;  // col -> weight row (c of V)
                int sb = n0 + wc + j * 16 + lq * 4;       // 4 contiguous s (quad rows)
                float bi = bias[1024 + c];
                floatx4 v = acc[i][j];
                *(unsigned int*)(dst + (size_t)c * S_ + sb) =
                    f2fp8x4(v[0] + bi, v[1] + bi, v[2] + bi, v[3] + bi);
            }
    }
}

// ---------------- scores: attn[i][j] = fp8(SCALE * Q[i].K[j]) ----------------
// SWAP so col<->i (per-lane), quad rows<->j (4-contiguous pack axis).
__global__ __launch_bounds__(256) void scores_mfma(const unsigned char* __restrict__ Qb,
                                                   const unsigned char* __restrict__ Kb,
                                                   unsigned char* __restrict__ attn) {
    GEMM_PROLOGUE
    const unsigned char* Ag = Qb + (size_t)b * (S_ * C_);
    const unsigned char* Bg = Kb + (size_t)b * (S_ * C_);
    mfma_loop<true>(Ag, C_, Bg, C_, C_, m0, n0, ldsA, ldsB, acc);
    unsigned char* ap = attn + (size_t)b * (S_ * S_);
    #pragma unroll
    for (int i = 0; i < 4; i++)
        #pragma unroll
        for (int j = 0; j < 4; j++) {
            int ii = m0 + wr + i * 16 + lrow;   // col -> Q row (i)
            int jb = n0 + wc + j * 16 + lq * 4; // quad rows -> K rows (j), contiguous 4
            floatx4 v = acc[i][j];
            *(unsigned int*)(ap + (size_t)ii * S_ + jb) =
                f2fp8x4(v[0] * SCALE_, v[1] * SCALE_, v[2] * SCALE_, v[3] * SCALE_);
        }
}

// ---------------- softmax rows (in place fp8, P scaled by 256) ----------------
__global__ __launch_bounds__(256) void softmax_rows(unsigned int* __restrict__ attn) {
    unsigned int* p = attn + (size_t)blockIdx.x * (S_ / 4);
    const int t = threadIdx.x;
    unsigned int u = p[t];
    auto lo = __builtin_amdgcn_cvt_pk_f32_fp8(u, false);
    auto hi = __builtin_amdgcn_cvt_pk_f32_fp8(u, true);
    float v0 = lo[0], v1 = lo[1], v2 = hi[0], v3 = hi[1];
    float m = fmaxf(fmaxf(v0, v1), fmaxf(v2, v3));
    #pragma unroll
    for (int o = 32; o; o >>= 1) m = fmaxf(m, __shfl_down(m, o));
    __shared__ float lm[4], lsum[4];
    const int wid = t >> 6, lane = t & 63;
    if (lane == 0) lm[wid] = m;
    __syncthreads();
    m = fmaxf(fmaxf(lm[0], lm[1]), fmaxf(lm[2], lm[3]));
    float e0 = __expf(v0 - m), e1 = __expf(v1 - m), e2 = __expf(v2 - m), e3 = __expf(v3 - m);
    float s = e0 + e1 + e2 + e3;
    #pragma unroll
    for (int o = 32; o; o >>= 1) s += __shfl_down(s, o);
    if (lane == 0) lsum[wid] = s;
    __syncthreads();
    float T = lsum[0] + lsum[1] + lsum[2] + lsum[3];
    float r = PSCL_ * __frcp_rn(T);
    p[t] = f2fp8x4(e0 * r, e1 * r, e2 * r, e3 * r);
}

// ---------------- PV: O[s][c] = fp8( (1/256) * sum_j P[s][j] V[c][j] ) ----------------
// SWAP so col<->s, quad rows<->c (4-contiguous pack axis).
__global__ __launch_bounds__(256) void pv_mfma(const unsigned char* __restrict__ attn,
                                               const unsigned char* __restrict__ Vb,
                                               unsigned char* __restrict__ Ob) {
    GEMM_PROLOGUE
    const unsigned char* Ag = attn + (size_t)b * (S_ * S_);
    const unsigned char* Bg = Vb + (size_t)b * (C_ * S_);
    mfma_loop<true>(Ag, S_, Bg, S_, S_, m0, n0, ldsA, ldsB, acc);
    unsigned char* op = Ob + (size_t)b * (S_ * C_);
    #pragma unroll
    for (int i = 0; i < 4; i++)
        #pragma unroll
        for (int j = 0; j < 4; j++) {
            int ii = m0 + wr + i * 16 + lrow;   // col -> P row (s)
            int cb = n0 + wc + j * 16 + lq * 4; // quad rows -> V rows (c), contiguous 4
            floatx4 v = acc[i][j];
            *(unsigned int*)(op + (size_t)ii * C_ + cb) =
                f2fp8x4(v[0] * IPSCL_, v[1] * IPSCL_, v[2] * IPSCL_, v[3] * IPSCL_);
        }
}

// ---------------- out projection + bias + residual (fp32 out) ----------------
__global__ __launch_bounds__(256) void out_mfma(const unsigned char* __restrict__ wo,
                                                const unsigned char* __restrict__ Ob,
                                                const float* __restrict__ bias,
                                                const float* __restrict__ x,
                                                float* __restrict__ out) {
    GEMM_PROLOGUE
    const unsigned char* Bg = Ob + (size_t)b * (S_ * C_);
    mfma_loop<false>(wo, C_, Bg, C_, C_, m0, n0, ldsA, ldsB, acc);
    const float* xb = x + (size_t)b * (C_ * S_);
    float* ob = out + (size_t)b * (C_ * S_);
    #pragma unroll
    for (int i = 0; i < 4; i++)
        #pragma unroll
        for (int j = 0; j < 4; j++) {
            int obase = m0 + wr + i * 16 + lq * 4;
            int s     = n0 + wc + j * 16 + lrow;
            float4 bi = *(const float4*)(bias + obase);
            floatx4 v = acc[i][j];
            float bb[4] = {bi.x, bi.y, bi.z, bi.w};
            #pragma unroll
            for (int r = 0; r < 4; r++) {
                size_t idx = (size_t)(obase + r) * S_ + s;
                ob[idx] = v[r] + bb[r] + xb[idx];
            }
        }
}

// ---------------- launch ----------------
extern "C" void kernel_launch(void* const* d_in, const int* in_sizes, int n_in,
                              void* d_out, int out_size, void* d_ws, size_t ws_size,
                              hipStream_t stream) {
    const float* x      = (const float*)d_in[0];
    const float* gamma  = (const float*)d_in[1];
    const float* beta   = (const float*)d_in[2];
    const float* w_qkv  = (const float*)d_in[3];
    const float* b_qkv  = (const float*)d_in[4];
    const float* w_out  = (const float*)d_in[5];
    const float* b_out  = (const float*)d_in[6];
    float* out          = (float*)d_out;

    char* ws = (char*)d_ws;
    // fp8 workspace layout (bytes), aliasing is stream-order safe:
    //   Qb   [b][1024][512] @ 0          (16 MB)
    //   Kb   [b][1024][512] @ 16 MB      (16 MB)
    //   Vb   [b][512][1024] @ 32 MB      (16 MB)
    //   xnt  [b][1024][512] @ 48 MB      (16 MB) -- dead after qkv
    //   attn [b][1024][1024] @ 64 MB     (32 MB)
    //   Ob   [b][1024][512] @ 48 MB      (16 MB) -- aliases xnt
    //   wqkv_fp8 @ 96 MB (768 KB), wout_fp8, stats
    unsigned char* Qb   = (unsigned char*)(ws);
    unsigned char* Kb   = (unsigned char*)(ws + 16777216ULL);
    unsigned char* Vb   = (unsigned char*)(ws + 33554432ULL);
    unsigned char* xnt  = (unsigned char*)(ws + 50331648ULL);
    unsigned char* attn = (unsigned char*)(ws + 67108864ULL);
    unsigned char* Ob   = (unsigned char*)(ws + 50331648ULL);
    unsigned char* wqkv8 = (unsigned char*)(ws + 100663296ULL);
    unsigned char* wout8 = (unsigned char*)(ws + 100663296ULL + 786432ULL);
    float2* stats        = (float2*)(ws + 100663296ULL + 786432ULL + 262144ULL);

    gn_stats  <<<B_ * G_, 256, 0, stream>>>(x, stats);
    cast_fp8  <<<C3_ * C_ / 1024, 256, 0, stream>>>(w_qkv, wqkv8);
    cast_fp8  <<<C_ * C_ / 1024, 256, 0, stream>>>(w_out, wout8);
    xnt_kernel<<<dim3(16, 8, B_), 256, 0, stream>>>(x, gamma, beta, stats, xnt);
    qkv_mfma  <<<dim3(8, 12, B_), 256, 0, stream>>>(wqkv8, xnt, b_qkv, Qb, Kb, Vb);
    scores_mfma<<<dim3(8, 8, B_), 256, 0, stream>>>(Qb, Kb, attn);
    softmax_rows<<<B_ * S_, 256, 0, stream>>>((unsigned int*)attn);
    pv_mfma   <<<dim3(4, 8, B_), 256, 0, stream>>>(attn, Vb, Ob);
    out_mfma  <<<dim3(8, 4, B_), 256, 0, stream>>>(wout8, Ob, b_out, x, out);
}

// Round 5
// 410.639 us; speedup vs baseline: 1.1719x; 1.1719x over previous
//
#include <hip/hip_runtime.h>
#include <hip/hip_bf16.h>

#define B_    32
#define C_    512
#define S_    1024
#define G_    32
#define CPG_  16
#define C3_   1536
#define EPS_  1e-5f
#define SCALE_ 0.044194173824159216f   // 1/sqrt(512), folded into K during qkv epilogue

typedef __attribute__((ext_vector_type(4))) float  floatx4;
typedef __attribute__((ext_vector_type(8))) __bf16 bf16x8;

__device__ __forceinline__ float bf2f(unsigned short u) {
    union { unsigned int i; float f; } v; v.i = ((unsigned int)u) << 16; return v.f;
}
__device__ __forceinline__ unsigned short f2bf(float f) {
    union { float f; unsigned int i; } v; v.f = f;
    unsigned int r = v.i + 0x7fffu + ((v.i >> 16) & 1u);
    return (unsigned short)(r >> 16);
}

// direct global->LDS DMA, 16 bytes per lane. LDS dest = wave-uniform base + lane*16.
__device__ __forceinline__ void gl16(const unsigned short* g, unsigned short* l) {
    __builtin_amdgcn_global_load_lds(
        (const __attribute__((address_space(1))) unsigned int*)g,
        (__attribute__((address_space(3))) unsigned int*)l, 16, 0, 0);
}

// ---------------- group-norm stats ----------------
__global__ __launch_bounds__(256) void gn_stats(const float* __restrict__ x,
                                                float2* __restrict__ stats) {
    const size_t base = (size_t)blockIdx.x * (CPG_ * S_);
    const float4* xp = (const float4*)(x + base);
    float s = 0.f, ss = 0.f;
    for (int i = threadIdx.x; i < (CPG_ * S_) / 4; i += 256) {
        float4 v = xp[i];
        s  += v.x + v.y + v.z + v.w;
        ss += v.x * v.x + v.y * v.y + v.z * v.z + v.w * v.w;
    }
    #pragma unroll
    for (int o = 32; o; o >>= 1) { s += __shfl_down(s, o); ss += __shfl_down(ss, o); }
    __shared__ float a1[4], a2[4];
    const int wid = threadIdx.x >> 6, lane = threadIdx.x & 63;
    if (lane == 0) { a1[wid] = s; a2[wid] = ss; }
    __syncthreads();
    if (threadIdx.x == 0) {
        float S  = a1[0] + a1[1] + a1[2] + a1[3];
        float SS = a2[0] + a2[1] + a2[2] + a2[3];
        float mean = S * (1.f / 16384.f);
        float var  = SS * (1.f / 16384.f) - mean * mean;
        stats[blockIdx.x] = make_float2(mean, rsqrtf(var + EPS_));
    }
}

// ---------------- fp32 -> bf16 convert ----------------
__global__ __launch_bounds__(256) void cast_bf16(const float* __restrict__ src,
                                                 unsigned short* __restrict__ dst) {
    int i = (blockIdx.x * 256 + threadIdx.x) * 4;
    float4 v = *(const float4*)(src + i);
    ushort4 o; o.x = f2bf(v.x); o.y = f2bf(v.y); o.z = f2bf(v.z); o.w = f2bf(v.w);
    *(ushort4*)(dst + i) = o;
}

// ---------------- normalized x, transposed to [b][s][c], bf16 ----------------
__global__ __launch_bounds__(256) void xnt_kernel(const float* __restrict__ x,
                                                  const float* __restrict__ gamma,
                                                  const float* __restrict__ beta,
                                                  const float2* __restrict__ stats,
                                                  unsigned short* __restrict__ xnt) {
    const int b = blockIdx.z, c0 = blockIdx.y * 64, s0 = blockIdx.x * 64;
    __shared__ float tile[64][65];
    const float* xb = x + (size_t)b * (C_ * S_);
    const int t = threadIdx.x, tr = t >> 4, tc4 = (t & 15) * 4;
    #pragma unroll
    for (int i = 0; i < 4; i++) {
        int r = tr + i * 16;
        int c = c0 + r;
        float2 mv = stats[b * G_ + (c >> 4)];
        float a  = mv.y * gamma[c];
        float bb = beta[c] - mv.x * a;
        float4 v = *(const float4*)(xb + (size_t)c * S_ + s0 + tc4);
        tile[r][tc4 + 0] = a * v.x + bb;
        tile[r][tc4 + 1] = a * v.y + bb;
        tile[r][tc4 + 2] = a * v.z + bb;
        tile[r][tc4 + 3] = a * v.w + bb;
    }
    __syncthreads();
    unsigned short* xo = xnt + (size_t)b * (S_ * C_);
    #pragma unroll
    for (int i = 0; i < 4; i++) {
        int sr = tr + i * 16;
        ushort4 o4;
        o4.x = f2bf(tile[tc4 + 0][sr]);
        o4.y = f2bf(tile[tc4 + 1][sr]);
        o4.z = f2bf(tile[tc4 + 2][sr]);
        o4.w = f2bf(tile[tc4 + 3][sr]);
        *(ushort4*)(xo + (size_t)(s0 + sr) * C_ + c0 + tc4) = o4;
    }
}

// ---------------- MFMA 128x128 mainloop, BK=64 (2x32 subtiles), global_load_lds ----------------
// C[m][n] = sum_k A[m][k]*B[n][k]; A,B bf16 K-contiguous.
// LDS per operand: 2 subtiles of [128][32] ushort (row stride 64 B = conflict-free b128).
// 32 MFMA between each barrier pair. SWAP passes (B,A) -> free output transpose.
template<bool SWAP>
__device__ __forceinline__ void mfma_loop(const unsigned short* __restrict__ Ag, int lda,
                                          const unsigned short* __restrict__ Bg, int ldb,
                                          int K, int m0, int n0,
                                          unsigned short* ldsA, unsigned short* ldsB,
                                          floatx4 (&acc)[4][4]) {
    const int t = threadIdx.x, lane = t & 63, wave = t >> 6;
    const int wr = (wave >> 1) * 64, wc = (wave & 1) * 64;
    const int lrow = lane & 15, lq = lane >> 4;
    // staging: per (subtile, half) a wave covers 16 rows x 32 ushort = 1024 B.
    const int srow = wave * 16 + (lane >> 2);   // row within a 64-row half
    const int scol = (lane & 3) * 8;            // ushort col within subtile
    const unsigned short* gA0 = Ag + (size_t)(m0 + srow) * lda + scol;
    const unsigned short* gA1 = gA0 + (size_t)64 * lda;
    const unsigned short* gB0 = Bg + (size_t)(n0 + srow) * ldb + scol;
    const unsigned short* gB1 = gB0 + (size_t)64 * ldb;
    unsigned short* lA = ldsA + wave * 512;     // + sub*4096 + half*2048
    unsigned short* lB = ldsB + wave * 512;
    for (int k0 = 0; k0 < K; k0 += 64) {
        gl16(gA0 + k0,      lA);
        gl16(gA1 + k0,      lA + 2048);
        gl16(gA0 + k0 + 32, lA + 4096);
        gl16(gA1 + k0 + 32, lA + 6144);
        gl16(gB0 + k0,      lB);
        gl16(gB1 + k0,      lB + 2048);
        gl16(gB0 + k0 + 32, lB + 4096);
        gl16(gB1 + k0 + 32, lB + 6144);
        __syncthreads();
        #pragma unroll
        for (int sub = 0; sub < 2; sub++) {
            bf16x8 af[4], bfr[4];
            #pragma unroll
            for (int i = 0; i < 4; i++) {
                af[i]  = *(const bf16x8*)(ldsA + sub * 4096 + (wr + i * 16 + lrow) * 32 + lq * 8);
                bfr[i] = *(const bf16x8*)(ldsB + sub * 4096 + (wc + i * 16 + lrow) * 32 + lq * 8);
            }
            #pragma unroll
            for (int i = 0; i < 4; i++)
                #pragma unroll
                for (int j = 0; j < 4; j++) {
                    if (SWAP)
                        acc[i][j] = __builtin_amdgcn_mfma_f32_16x16x32_bf16(bfr[j], af[i], acc[i][j], 0, 0, 0);
                    else
                        acc[i][j] = __builtin_amdgcn_mfma_f32_16x16x32_bf16(af[i], bfr[j], acc[i][j], 0, 0, 0);
                }
        }
        __syncthreads();
    }
}

#define GEMM_PROLOGUE                                                   \
    __shared__ __align__(16) unsigned short ldsA[2 * 128 * 32];         \
    __shared__ __align__(16) unsigned short ldsB[2 * 128 * 32];         \
    const int b = blockIdx.z;                                           \
    const int m0 = blockIdx.y * 128, n0 = blockIdx.x * 128;             \
    const int t = threadIdx.x, lane = t & 63, wave = t >> 6;            \
    const int wr = (wave >> 1) * 64, wc = (wave & 1) * 64;              \
    const int lrow = lane & 15, lq = lane >> 4;                         \
    floatx4 acc[4][4];                                                  \
    _Pragma("unroll") for (int i = 0; i < 4; i++)                       \
        _Pragma("unroll") for (int j = 0; j < 4; j++)                   \
            acc[i][j] = (floatx4){0.f, 0.f, 0.f, 0.f};

// ---------------- QKV projection ----------------
// A = wqkv_bf [1536][512], B = xnt[b] [1024][512].
// m-tiles 0-7 -> Q,K stored [s][c] (K pre-scaled by SCALE_), 8-11 -> V[c][s] (SWAP).
__global__ __launch_bounds__(256, 4) void qkv_mfma(const unsigned short* __restrict__ wbf,
                                                   const unsigned short* __restrict__ xnt,
                                                   const float* __restrict__ bias,
                                                   unsigned short* __restrict__ Qb,
                                                   unsigned short* __restrict__ Kb,
                                                   unsigned short* __restrict__ Vb) {
    GEMM_PROLOGUE
    const unsigned short* Bg = xnt + (size_t)b * (S_ * C_);
    if (m0 < 1024) {
        mfma_loop<false>(wbf, C_, Bg, C_, C_, m0, n0, ldsA, ldsB, acc);
        unsigned short* dst = (m0 < 512 ? Qb : Kb) + (size_t)b * (S_ * C_);
        const int osec = (m0 < 512) ? 0 : 512;
        const float sc = (m0 < 512) ? 1.f : SCALE_;
        #pragma unroll
        for (int i = 0; i < 4; i++)
            #pragma unroll
            for (int j = 0; j < 4; j++) {
                int oabs = m0 + wr + i * 16 + lq * 4;
                int s    = n0 + wc + j * 16 + lrow;
                float4 bi = *(const float4*)(bias + oabs);
                floatx4 v = acc[i][j];
                ushort4 o4;
                o4.x = f2bf((v[0] + bi.x) * sc); o4.y = f2bf((v[1] + bi.y) * sc);
                o4.z = f2bf((v[2] + bi.z) * sc); o4.w = f2bf((v[3] + bi.w) * sc);
                *(ushort4*)(dst + (size_t)s * C_ + (oabs - osec)) = o4;
            }
    } else {
        mfma_loop<true>(wbf, C_, Bg, C_, C_, m0, n0, ldsA, ldsB, acc);
        unsigned short* dst = Vb + (size_t)b * (C_ * S_);
        #pragma unroll
        for (int i = 0; i < 4; i++)
            #pragma unroll
            for (int j = 0; j < 4; j++) {
                int c  = m0 - 1024 + wr + i * 16 + lrow;   // cols index m (o)
                int sb = n0 + wc + j * 16 + lq * 4;        // rows index n (s)
                float bi = bias[1024 + c];
                floatx4 v = acc[i][j];
                ushort4 o4;
                o4.x = f2bf(v[0] + bi); o4.y = f2bf(v[1] + bi);
                o4.z = f2bf(v[2] + bi); o4.w = f2bf(v[3] + bi);
                *(ushort4*)(dst + (size_t)c * S_ + sb) = o4;
            }
    }
}

// ---------------- scores: attn[i][j] = Q[i][:] . K[j][:]  (scale already in K) ----------------
__global__ __launch_bounds__(256, 4) void scores_mfma(const unsigned short* __restrict__ Qb,
                                                      const unsigned short* __restrict__ Kb,
                                                      unsigned short* __restrict__ attn) {
    GEMM_PROLOGUE
    const unsigned short* Ag = Qb + (size_t)b * (S_ * C_);
    const unsigned short* Bg = Kb + (size_t)b * (S_ * C_);
    mfma_loop<false>(Ag, C_, Bg, C_, C_, m0, n0, ldsA, ldsB, acc);
    unsigned short* ap = attn + (size_t)b * (S_ * S_);
    #pragma unroll
    for (int i = 0; i < 4; i++)
        #pragma unroll
        for (int j = 0; j < 4; j++) {
            int jj = n0 + wc + j * 16 + lrow;
            int ib = m0 + wr + i * 16 + lq * 4;
            floatx4 v = acc[i][j];
            #pragma unroll
            for (int r = 0; r < 4; r++)
                ap[(size_t)(ib + r) * S_ + jj] = f2bf(v[r]);
        }
}

// ---------------- softmax rows (in place bf16) ----------------
__global__ __launch_bounds__(256) void softmax_rows(unsigned short* __restrict__ attn) {
    unsigned short* p = attn + (size_t)blockIdx.x * S_;
    const int t = threadIdx.x;
    ushort4 uv = *(const ushort4*)(p + t * 4);
    float v0 = bf2f(uv.x), v1 = bf2f(uv.y), v2 = bf2f(uv.z), v3 = bf2f(uv.w);
    float m = fmaxf(fmaxf(v0, v1), fmaxf(v2, v3));
    #pragma unroll
    for (int o = 32; o; o >>= 1) m = fmaxf(m, __shfl_down(m, o));
    __shared__ float lm[4], lsum[4];
    const int wid = t >> 6, lane = t & 63;
    if (lane == 0) lm[wid] = m;
    __syncthreads();
    m = fmaxf(fmaxf(lm[0], lm[1]), fmaxf(lm[2], lm[3]));
    float e0 = __expf(v0 - m), e1 = __expf(v1 - m), e2 = __expf(v2 - m), e3 = __expf(v3 - m);
    float s = e0 + e1 + e2 + e3;
    #pragma unroll
    for (int o = 32; o; o >>= 1) s += __shfl_down(s, o);
    if (lane == 0) lsum[wid] = s;
    __syncthreads();
    float T = lsum[0] + lsum[1] + lsum[2] + lsum[3];
    float r = __frcp_rn(T);
    ushort4 ov;
    ov.x = f2bf(e0 * r); ov.y = f2bf(e1 * r); ov.z = f2bf(e2 * r); ov.w = f2bf(e3 * r);
    *(ushort4*)(p + t * 4) = ov;
}

// ---------------- PV: O[i][c] = sum_j P[i][j] V[c][j] ----------------
__global__ __launch_bounds__(256, 4) void pv_mfma(const unsigned short* __restrict__ attn,
                                                  const unsigned short* __restrict__ Vb,
                                                  unsigned short* __restrict__ Ob) {
    GEMM_PROLOGUE
    const unsigned short* Ag = attn + (size_t)b * (S_ * S_);
    const unsigned short* Bg = Vb + (size_t)b * (C_ * S_);
    mfma_loop<false>(Ag, S_, Bg, S_, S_, m0, n0, ldsA, ldsB, acc);
    unsigned short* op = Ob + (size_t)b * (S_ * C_);
    #pragma unroll
    for (int i = 0; i < 4; i++)
        #pragma unroll
        for (int j = 0; j < 4; j++) {
            int cc = n0 + wc + j * 16 + lrow;
            int ib = m0 + wr + i * 16 + lq * 4;
            floatx4 v = acc[i][j];
            #pragma unroll
            for (int r = 0; r < 4; r++)
                op[(size_t)(ib + r) * C_ + cc] = f2bf(v[r]);
        }
}

// ---------------- out projection + bias + residual ----------------
__global__ __launch_bounds__(256, 4) void out_mfma(const unsigned short* __restrict__ wbf,
                                                   const unsigned short* __restrict__ Ob,
                                                   const float* __restrict__ bias,
                                                   const float* __restrict__ x,
                                                   float* __restrict__ out) {
    GEMM_PROLOGUE
    const unsigned short* Bg = Ob + (size_t)b * (S_ * C_);
    mfma_loop<false>(wbf, C_, Bg, C_, C_, m0, n0, ldsA, ldsB, acc);
    const float* xb = x + (size_t)b * (C_ * S_);
    float* ob = out + (size_t)b * (C_ * S_);
    #pragma unroll
    for (int i = 0; i < 4; i++)
        #pragma unroll
        for (int j = 0; j < 4; j++) {
            int obase = m0 + wr + i * 16 + lq * 4;
            int s     = n0 + wc + j * 16 + lrow;
            float4 bi = *(const float4*)(bias + obase);
            floatx4 v = acc[i][j];
            float bb[4] = {bi.x, bi.y, bi.z, bi.w};
            #pragma unroll
            for (int r = 0; r < 4; r++) {
                size_t idx = (size_t)(obase + r) * S_ + s;
                ob[idx] = v[r] + bb[r] + xb[idx];
            }
        }
}

// ---------------- launch ----------------
extern "C" void kernel_launch(void* const* d_in, const int* in_sizes, int n_in,
                              void* d_out, int out_size, void* d_ws, size_t ws_size,
                              hipStream_t stream) {
    const float* x      = (const float*)d_in[0];
    const float* gamma  = (const float*)d_in[1];
    const float* beta   = (const float*)d_in[2];
    const float* w_qkv  = (const float*)d_in[3];
    const float* b_qkv  = (const float*)d_in[4];
    const float* w_out  = (const float*)d_in[5];
    const float* b_out  = (const float*)d_in[6];
    float* out          = (float*)d_out;

    char* ws = (char*)d_ws;
    // layout (bytes), aliasing is stream-order safe:
    //   Qb   [b][1024][512] bf16 @ 0         (32 MB)  -- dead after scores
    //   Kb   [b][1024][512] bf16 @ 32 MB     (32 MB)
    //   Vb   [b][512][1024] bf16 @ 64 MB     (32 MB)
    //   xnt  [b][1024][512] bf16 @ 96 MB     (32 MB)  -- dead after qkv
    //   attn [b][1024][1024] bf16 @ 96 MB    (64 MB)  -- aliases xnt
    //   Ob   [b][1024][512] bf16 @ 0         (32 MB)  -- aliases Qb
    //   wqkv_bf @ 160 MB, wout_bf, stats     (~2.1 MB)
    unsigned short* Qb   = (unsigned short*)(ws);
    unsigned short* Kb   = (unsigned short*)(ws + 33554432ULL);
    unsigned short* Vb   = (unsigned short*)(ws + 67108864ULL);
    unsigned short* xnt  = (unsigned short*)(ws + 100663296ULL);
    unsigned short* attn = (unsigned short*)(ws + 100663296ULL);
    unsigned short* Ob   = (unsigned short*)(ws);
    unsigned short* wqkv_bf = (unsigned short*)(ws + 167772160ULL);
    unsigned short* wout_bf = (unsigned short*)(ws + 167772160ULL + 1572864ULL);
    float2* stats           = (float2*)(ws + 167772160ULL + 1572864ULL + 524288ULL);

    gn_stats  <<<B_ * G_, 256, 0, stream>>>(x, stats);
    cast_bf16 <<<C3_ * C_ / 1024, 256, 0, stream>>>(w_qkv, wqkv_bf);
    cast_bf16 <<<C_ * C_ / 1024, 256, 0, stream>>>(w_out, wout_bf);
    xnt_kernel<<<dim3(16, 8, B_), 256, 0, stream>>>(x, gamma, beta, stats, xnt);
    qkv_mfma  <<<dim3(8, 12, B_), 256, 0, stream>>>(wqkv_bf, xnt, b_qkv, Qb, Kb, Vb);
    scores_mfma<<<dim3(8, 8, B_), 256, 0, stream>>>(Qb, Kb, attn);
    softmax_rows<<<B_ * S_, 256, 0, stream>>>(attn);
    pv_mfma   <<<dim3(4, 8, B_), 256, 0, stream>>>(attn, Vb, Ob);
    out_mfma  <<<dim3(8, 4, B_), 256, 0, stream>>>(wout_bf, Ob, b_out, x, out);
}